// Round 6
// baseline (119.638 us; speedup 1.0000x reference)
//
#include <hip/hip_runtime.h>

#define NB 64
#define NI 1024
#define NO 1024
#define IROWS (NI + 1)
#define S_SPLIT 64
#define TJ 64
#define NOUT (NB * NO)      // 65536 outputs
#define MAXBLK 256          // blocks in maxabs stage

__device__ __forceinline__ float fast_exp2(float x) { return __builtin_amdgcn_exp2f(x); }
__device__ __forceinline__ float fast_log2(float x) { return __builtin_amdgcn_logf(x); }

// ---- Pass 1: per-block max|W| over {w_pos, w_neg, b_pos, b_neg} -> ws_max[256] ----
__global__ __launch_bounds__(256) void maxabs_stage(
    const float4* __restrict__ wp4, const float4* __restrict__ wn4,
    const float* __restrict__ bp, const float* __restrict__ bn,
    float* __restrict__ ws_max)
{
    const int tid = blockIdx.x * 256 + threadIdx.x;
    const int NW4 = NI * NO / 4;                 // 262144 float4 per matrix
    float m = 0.0f;
    for (int idx = tid; idx < NW4; idx += MAXBLK * 256) {
        float4 a = wp4[idx], b = wn4[idx];
        m = fmaxf(m, fmaxf(fmaxf(fabsf(a.x), fabsf(a.y)), fmaxf(fabsf(a.z), fabsf(a.w))));
        m = fmaxf(m, fmaxf(fmaxf(fabsf(b.x), fabsf(b.y)), fmaxf(fabsf(b.z), fabsf(b.w))));
    }
    if (tid < NO) m = fmaxf(m, fmaxf(fabsf(bp[tid]), fabsf(bn[tid])));

    #pragma unroll
    for (int off = 32; off > 0; off >>= 1)
        m = fmaxf(m, __shfl_xor(m, off));
    __shared__ float wm[4];
    if ((threadIdx.x & 63) == 0) wm[threadIdx.x >> 6] = m;
    __syncthreads();
    if (threadIdx.x == 0)
        ws_max[blockIdx.x] = fmaxf(fmaxf(wm[0], wm[1]), fmaxf(wm[2], wm[3]));
}

// block-wide re-reduction of the 256 partial maxes (cheap, L2-hot)
__device__ __forceinline__ float block_maxw(const float* __restrict__ ws_max, int tid)
{
    float m = ws_max[tid & 255];
    #pragma unroll
    for (int off = 32; off > 0; off >>= 1)
        m = fmaxf(m, __shfl_xor(m, off));
    __shared__ float wm[4];
    if ((tid & 63) == 0) wm[tid >> 6] = m;
    __syncthreads();
    return fmaxf(fmaxf(wm[0], wm[1]), fmaxf(wm[2], wm[3]));
}

// ---- Pass 2: main compute. G folded into exponent: G*r^e = exp2(e*L + log2 G) ----
// Block: 256 thr = 64 j-pairs (tx) x 4 b-groups (ty); thread owns 16 b rows.
// Grid: (NO/TJ) j-tiles x S_SPLIT i-chunks (1024 blocks = 4/CU). Partials -> ws.
__global__ __launch_bounds__(256) void memristor_main(
    const float* __restrict__ x,
    const float* __restrict__ w_pos, const float* __restrict__ w_neg,
    const float* __restrict__ b_pos, const float* __restrict__ b_neg,
    const float* __restrict__ n_param,
    const float* __restrict__ ws_max,
    float* __restrict__ partial)
{
    const int tid = threadIdx.x;
    const float maxw = block_maxw(ws_max, tid);
    const float k_G = 0.9f / maxw;

    // [local_i][b] layout (+1 float2 pad): inner-loop reads are 128B contiguous
    // per thread (merge to ds_read_b128); staging writes are 2-way aliased (free).
    __shared__ float2 LS[17][65];

    const int jt = blockIdx.x;
    const int s  = blockIdx.y;
    const int base  = IROWS / S_SPLIT;   // 16
    const int extra = IROWS % S_SPLIT;   // 1
    const int i0  = s * base + min(s, extra);
    const int len = base + (s < extra ? 1 : 0);   // 16 or 17

    {
        const int li = tid & 63;
        if (li < len) {
            const int gi = i0 + li;
            #pragma unroll 4
            for (int bb = tid >> 6; bb < NB; bb += 4) {
                float v  = (gi < NI) ? x[bb * NI + gi] : 1.0f;   // ones column
                float sg = (v > 0.0f) ? 1.0f : ((v < 0.0f) ? -1.0f : 0.0f);
                float L  = fast_log2(fabsf(v)) + 1.0f;           // log2(2|v|); v=0 -> -inf (ok)
                LS[li][bb] = make_float2(L, sg);
            }
        }
    }
    __syncthreads();

    const int tx = tid & 63;
    const int ty = tid >> 6;
    const int jp = jt * TJ + tx;

    float acc[16];
    #pragma unroll
    for (int k = 0; k < 16; ++k) acc[k] = 0.0f;

    const int reg_len = min(len, NI - i0);
    for (int ii = 0; ii < reg_len; ++ii) {
        const int gi = i0 + ii;
        const float2 n2 = reinterpret_cast<const float2*>(n_param + (size_t)gi * 2 * NO)[jp];
        const float ep   = fast_log2(n2.x);
        const float en   = fast_log2(n2.y);
        const float lgGp = fast_log2(fmaf(k_G, w_pos[gi * NO + jp], 0.1f));  // G>0 guaranteed
        const float lgGn = fast_log2(fmaf(k_G, w_neg[gi * NO + jp], 0.1f));
        const float2* lsrow = &LS[ii][ty * 16];
        #pragma unroll
        for (int k = 0; k < 16; ++k) {
            const float2 ls = lsrow[k];               // wave-uniform broadcast
            const float Pp = fast_exp2(fmaf(ep, ls.x, lgGp));
            const float Pn = fast_exp2(fmaf(en, ls.x, lgGn));
            acc[k] = fmaf(ls.y, Pp - Pn, acc[k]);
        }
    }

    if (i0 + len > NI) {   // bias row (gi == NI) at local index len-1
        const int ii = len - 1;
        const float2 n2 = reinterpret_cast<const float2*>(n_param + (size_t)NI * 2 * NO)[jp];
        const float ep   = fast_log2(n2.x);
        const float en   = fast_log2(n2.y);
        const float lgGp = fast_log2(fmaf(k_G, b_pos[jp], 0.1f));
        const float lgGn = fast_log2(fmaf(k_G, b_neg[jp], 0.1f));
        const float2* lsrow = &LS[ii][ty * 16];
        #pragma unroll
        for (int k = 0; k < 16; ++k) {
            const float2 ls = lsrow[k];
            const float Pp = fast_exp2(fmaf(ep, ls.x, lgGp));
            const float Pn = fast_exp2(fmaf(en, ls.x, lgGn));
            acc[k] = fmaf(ls.y, Pp - Pn, acc[k]);
        }
    }

    float* slice = partial + (size_t)s * NOUT;
    #pragma unroll
    for (int k = 0; k < 16; ++k)
        slice[(ty * 16 + k) * NO + jp] = acc[k];
}

// ---- Pass 3: sum S_SPLIT partials per output, apply scale ----
__global__ __launch_bounds__(256) void reduce_kernel(
    const float* __restrict__ partial,
    const float* __restrict__ ws_max,
    float* __restrict__ y)
{
    const int tid = threadIdx.x;
    const float maxw = block_maxw(ws_max, tid);
    const int o = blockIdx.x * 256 + tid;
    float sum = 0.0f;
    #pragma unroll
    for (int p = 0; p < S_SPLIT; ++p)
        sum += partial[(size_t)p * NOUT + o];
    // y = V_REF/(k_V*k_G) * sum = 0.5/k_G * sum = 0.5*maxw/0.9 * sum
    y[o] = sum * (0.5f * maxw / 0.9f);
}

extern "C" void kernel_launch(void* const* d_in, const int* in_sizes, int n_in,
                              void* d_out, int out_size, void* d_ws, size_t ws_size,
                              hipStream_t stream)
{
    const float* x     = (const float*)d_in[0];
    const float* w_pos = (const float*)d_in[1];
    const float* w_neg = (const float*)d_in[2];
    const float* b_pos = (const float*)d_in[3];
    const float* b_neg = (const float*)d_in[4];
    const float* n_par = (const float*)d_in[5];
    float*    y        = (float*)d_out;

    float* ws_max  = (float*)d_ws;                       // 256 floats
    float* partial = (float*)d_ws + 1024;                // 64*65536 floats = 16 MB

    maxabs_stage<<<MAXBLK, 256, 0, stream>>>(
        (const float4*)w_pos, (const float4*)w_neg, b_pos, b_neg, ws_max);

    dim3 grid(NO / TJ, S_SPLIT);
    memristor_main<<<grid, 256, 0, stream>>>(x, w_pos, w_neg, b_pos, b_neg, n_par,
                                             ws_max, partial);

    reduce_kernel<<<NOUT / 256, 256, 0, stream>>>(partial, ws_max, y);
}

// Round 9
// 110.903 us; speedup vs baseline: 1.0788x; 1.0788x over previous
//
#include <hip/hip_runtime.h>

#define NB 64
#define NI 1024
#define NO 1024
#define IROWS (NI + 1)
#define S_SPLIT 32
#define TJ 64
#define NOUT (NB * NO)      // 65536 outputs
#define MAXBLK 256          // blocks in maxabs stage

__device__ __forceinline__ float fast_exp2(float x) { return __builtin_amdgcn_exp2f(x); }
__device__ __forceinline__ float fast_log2(float x) { return __builtin_amdgcn_logf(x); }

// ---- Pass 1: per-block max|W| over {w_pos, w_neg, b_pos, b_neg} -> ws_max[256] ----
__global__ __launch_bounds__(256) void maxabs_stage(
    const float4* __restrict__ wp4, const float4* __restrict__ wn4,
    const float* __restrict__ bp, const float* __restrict__ bn,
    float* __restrict__ ws_max)
{
    const int tid = blockIdx.x * 256 + threadIdx.x;
    const int NW4 = NI * NO / 4;                 // 262144 float4 per matrix
    float m = 0.0f;
    for (int idx = tid; idx < NW4; idx += MAXBLK * 256) {
        float4 a = wp4[idx], b = wn4[idx];
        m = fmaxf(m, fmaxf(fmaxf(fabsf(a.x), fabsf(a.y)), fmaxf(fabsf(a.z), fabsf(a.w))));
        m = fmaxf(m, fmaxf(fmaxf(fabsf(b.x), fabsf(b.y)), fmaxf(fabsf(b.z), fabsf(b.w))));
    }
    if (tid < NO) m = fmaxf(m, fmaxf(fabsf(bp[tid]), fabsf(bn[tid])));

    #pragma unroll
    for (int off = 32; off > 0; off >>= 1)
        m = fmaxf(m, __shfl_xor(m, off));
    __shared__ float wm[4];
    if ((threadIdx.x & 63) == 0) wm[threadIdx.x >> 6] = m;
    __syncthreads();
    if (threadIdx.x == 0)
        ws_max[blockIdx.x] = fmaxf(fmaxf(wm[0], wm[1]), fmaxf(wm[2], wm[3]));
}

// block-wide re-reduction of the 256 partial maxes (cheap, L2-hot)
__device__ __forceinline__ float block_maxw(const float* __restrict__ ws_max, int tid)
{
    float m = ws_max[tid & 255];
    #pragma unroll
    for (int off = 32; off > 0; off >>= 1)
        m = fmaxf(m, __shfl_xor(m, off));
    __shared__ float wm[4];
    if ((tid & 63) == 0) wm[tid >> 6] = m;
    __syncthreads();
    return fmaxf(fmaxf(wm[0], wm[1]), fmaxf(wm[2], wm[3]));
}

// ---- Pass 2: main compute. G folded into exponent: G*r^e = exp2(e*L + log2 G) ----
// Block: 256 thr = 64 j-pairs (tx) x 4 b-groups (ty); thread owns 16 b rows.
// Grid: (NO/TJ) j-tiles x S_SPLIT i-chunks (512 blocks = 2/CU). Partials -> ws.
__global__ __launch_bounds__(256) void memristor_main(
    const float* __restrict__ x,
    const float* __restrict__ w_pos, const float* __restrict__ w_neg,
    const float* __restrict__ b_pos, const float* __restrict__ b_neg,
    const float* __restrict__ n_param,
    const float* __restrict__ ws_max,
    float* __restrict__ partial)
{
    const int tid = threadIdx.x;
    const float maxw = block_maxw(ws_max, tid);
    const float k_G = 0.9f / maxw;

    // [local_i][b] layout (+1 float2 pad): each thread's 16 float2 per ii are a
    // contiguous 128B run (merges to ds_read_b128, wave-uniform broadcast).
    __shared__ float2 LS[33][65];

    const int jt = blockIdx.x;
    const int s  = blockIdx.y;
    const int base  = IROWS / S_SPLIT;   // 32
    const int extra = IROWS % S_SPLIT;   // 1
    const int i0  = s * base + min(s, extra);
    const int len = base + (s < extra ? 1 : 0);   // 32 or 33

    {
        const int li = tid & 63;
        if (li < len) {
            const int gi = i0 + li;
            #pragma unroll 4
            for (int bb = tid >> 6; bb < NB; bb += 4) {
                float v  = (gi < NI) ? x[bb * NI + gi] : 1.0f;   // ones column
                float sg = (v > 0.0f) ? 1.0f : ((v < 0.0f) ? -1.0f : 0.0f);
                float L  = fast_log2(fabsf(v)) + 1.0f;           // log2(2|v|); v=0 -> -inf (ok)
                LS[li][bb] = make_float2(L, sg);
            }
        }
    }
    __syncthreads();

    const int tx = tid & 63;
    const int ty = tid >> 6;
    const int jp = jt * TJ + tx;

    float acc[16];
    #pragma unroll
    for (int k = 0; k < 16; ++k) acc[k] = 0.0f;

    const int reg_len = min(len, NI - i0);
    #pragma unroll 2
    for (int ii = 0; ii < reg_len; ++ii) {
        const int gi = i0 + ii;
        const float2 n2 = reinterpret_cast<const float2*>(n_param + (size_t)gi * 2 * NO)[jp];
        const float ep   = fast_log2(n2.x);
        const float en   = fast_log2(n2.y);
        const float lgGp = fast_log2(fmaf(k_G, w_pos[gi * NO + jp], 0.1f));  // G>0 guaranteed
        const float lgGn = fast_log2(fmaf(k_G, w_neg[gi * NO + jp], 0.1f));
        const float2* lsrow = &LS[ii][ty * 16];
        #pragma unroll
        for (int k = 0; k < 16; ++k) {
            const float2 ls = lsrow[k];               // wave-uniform broadcast
            const float Pp = fast_exp2(fmaf(ep, ls.x, lgGp));
            const float Pn = fast_exp2(fmaf(en, ls.x, lgGn));
            acc[k] = fmaf(ls.y, Pp - Pn, acc[k]);
        }
    }

    if (i0 + len > NI) {   // bias row (gi == NI) at local index len-1
        const int ii = len - 1;
        const float2 n2 = reinterpret_cast<const float2*>(n_param + (size_t)NI * 2 * NO)[jp];
        const float ep   = fast_log2(n2.x);
        const float en   = fast_log2(n2.y);
        const float lgGp = fast_log2(fmaf(k_G, b_pos[jp], 0.1f));
        const float lgGn = fast_log2(fmaf(k_G, b_neg[jp], 0.1f));
        const float2* lsrow = &LS[ii][ty * 16];
        #pragma unroll
        for (int k = 0; k < 16; ++k) {
            const float2 ls = lsrow[k];
            const float Pp = fast_exp2(fmaf(ep, ls.x, lgGp));
            const float Pn = fast_exp2(fmaf(en, ls.x, lgGn));
            acc[k] = fmaf(ls.y, Pp - Pn, acc[k]);
        }
    }

    float* slice = partial + (size_t)s * NOUT;
    #pragma unroll
    for (int k = 0; k < 16; ++k)
        slice[(ty * 16 + k) * NO + jp] = acc[k];
}

// ---- Pass 3: sum S_SPLIT partials per output (float4), apply scale ----
__global__ __launch_bounds__(256) void reduce_kernel(
    const float4* __restrict__ partial4,
    const float* __restrict__ ws_max,
    float* __restrict__ y)
{
    const int tid = threadIdx.x;
    const float maxw = block_maxw(ws_max, tid);
    const int o4 = blockIdx.x * 256 + tid;           // float4 index
    float4 sum = make_float4(0.f, 0.f, 0.f, 0.f);
    #pragma unroll
    for (int p = 0; p < S_SPLIT; ++p) {
        float4 v = partial4[(size_t)p * (NOUT / 4) + o4];
        sum.x += v.x; sum.y += v.y; sum.z += v.z; sum.w += v.w;
    }
    // y = V_REF/(k_V*k_G) * sum = 0.5/k_G * sum = 0.5*maxw/0.9 * sum
    const float sc = 0.5f * maxw / 0.9f;
    float4 out = make_float4(sum.x * sc, sum.y * sc, sum.z * sc, sum.w * sc);
    reinterpret_cast<float4*>(y)[o4] = out;
}

extern "C" void kernel_launch(void* const* d_in, const int* in_sizes, int n_in,
                              void* d_out, int out_size, void* d_ws, size_t ws_size,
                              hipStream_t stream)
{
    const float* x     = (const float*)d_in[0];
    const float* w_pos = (const float*)d_in[1];
    const float* w_neg = (const float*)d_in[2];
    const float* b_pos = (const float*)d_in[3];
    const float* b_neg = (const float*)d_in[4];
    const float* n_par = (const float*)d_in[5];
    float*    y        = (float*)d_out;

    float* ws_max  = (float*)d_ws;                       // 256 floats
    float* partial = (float*)d_ws + 1024;                // 32*65536 floats = 8 MB

    maxabs_stage<<<MAXBLK, 256, 0, stream>>>(
        (const float4*)w_pos, (const float4*)w_neg, b_pos, b_neg, ws_max);

    dim3 grid(NO / TJ, S_SPLIT);
    memristor_main<<<grid, 256, 0, stream>>>(x, w_pos, w_neg, b_pos, b_neg, n_par,
                                             ws_max, partial);

    reduce_kernel<<<NOUT / 4 / 256, 256, 0, stream>>>(
        (const float4*)partial, ws_max, y);
}